// Round 1
// 334.952 us; speedup vs baseline: 1.0200x; 1.0200x over previous
//
#include <hip/hip_runtime.h>

// Problem constants (fixed by the reference file)
constexpr int cN0  = 200000;   // num src nodes
constexpr int cN1  = 100000;   // num_dst layer 1
constexpr int cN2  = 50000;    // num_dst layer 2
constexpr int cE0  = 1600000;
constexpr int cE1  = 800000;
constexpr int cIN  = 128;      // IN_F
constexpr int cH   = 256;      // H_F
constexpr int cCLS = 64;       // N_CLS

// int8 quantization of x (values ~N(0,1); clip at +-6 sigma)
constexpr float QSTEP = 6.0f / 127.0f;
constexpr float QINV  = 127.0f / 6.0f;

using bf16x8 = __attribute__((ext_vector_type(8))) short;   // 8 bf16 = 4 VGPRs
using f32x4  = __attribute__((ext_vector_type(4))) float;

__device__ __forceinline__ float bflo(unsigned int u) {
    union { unsigned int i; float f; } v; v.i = u << 16; return v.f;
}
__device__ __forceinline__ float bfhi(unsigned int u) {
    union { unsigned int i; float f; } v; v.i = u & 0xFFFF0000u; return v.f;
}
__device__ __forceinline__ unsigned int f2bf(float f) {   // RNE
    union { float f; unsigned int i; } v; v.f = f;
    return (v.i + 0x7FFFu + ((v.i >> 16) & 1u)) >> 16;
}

// ---- prep: one kernel for all preprocessing ----
// Region A: rows < cN1  -> xb (bf16) + xq (biased u8). 8 float4/thread, dense lanes.
// Region B: rows >= cN1 -> xq only.
// Region W: weight transposes.  Region R: CSR row-pointer binary searches.
constexpr int PV   = 8;                              // float4 per thread (ILP)
constexpr int AF4  = cN1 * cIN / 4;                  // 3,200,000 float4
constexpr int ABLK = (AF4 + 256 * PV - 1) / (256 * PV);      // 1563
constexpr int BF4  = (cN0 - cN1) * cIN / 4;          // 3,200,000 float4
constexpr int BBLK = (BF4 + 256 * PV - 1) / (256 * PV);      // 1563
constexpr int WCNT = cH * cH + 2 * cCLS * cH;        // 98304
constexpr int WBLK = WCNT / 256;                     // 384
constexpr int RCNT = (cN1 + 1) + (cN2 + 1);          // 150002
constexpr int RBLK = (RCNT + 255) / 256;             // 586

__global__ __launch_bounds__(256) void prep(
        const float* __restrict__ x,
        const float* __restrict__ Ws1, const float* __restrict__ Wn1,
        const float* __restrict__ Wn2, const float* __restrict__ Ws2,
        const int* __restrict__ dst0, const int* __restrict__ dst1,
        unsigned short* __restrict__ xb, unsigned int* __restrict__ xq,
        unsigned short* __restrict__ Wt1, unsigned short* __restrict__ Wt2,
        int* __restrict__ row0, int* __restrict__ row1) {
    const int b = blockIdx.x, tid = threadIdx.x;
    if (b < ABLK + BBLK) {
        const bool hasXB = (b < ABLK);
        const int  lb    = hasXB ? b : b - ABLK;
        const int  limit = hasXB ? AF4 : BF4;
        const int  base  = lb * 256 * PV + tid;
        const float4* xp = (const float4*)x + (hasXB ? 0 : (size_t)AF4);
        const int  xqoff = hasXB ? 0 : AF4;

        float4 v[PV];
        #pragma unroll
        for (int j = 0; j < PV; ++j) {           // 8 independent loads in flight
            int idx = base + j * 256;
            int cidx = idx < limit ? idx : limit - 1;
            v[j] = xp[cidx];
        }
        auto q8b = [](float f) -> unsigned int { // biased: q+128 in [1,255]
            int q = __float2int_rn(f * QINV);
            q = q > 127 ? 127 : (q < -127 ? -127 : q);
            return (unsigned int)(q + 128);
        };
        #pragma unroll
        for (int j = 0; j < PV; ++j) {
            int idx = base + j * 256;
            if (idx >= limit) continue;
            float4 a = v[j];
            if (hasXB) {
                uint2 o;
                o.x = f2bf(a.x) | (f2bf(a.y) << 16);
                o.y = f2bf(a.z) | (f2bf(a.w) << 16);
                ((uint2*)xb)[idx] = o;
            }
            unsigned int d = q8b(a.x) | (q8b(a.y) << 8) |
                             (q8b(a.z) << 16) | (q8b(a.w) << 24);
            xq[xqoff + idx] = d;
        }
    } else if (b < ABLK + BBLK + WBLK) {
        const int wi = (b - ABLK - BBLK) * 256 + tid;
        if (wi < cH * cH) {
            int n = wi >> 8, k = wi & 255;
            float v = (k < cIN) ? Ws1[k * cH + n] : Wn1[(k - cIN) * cH + n];
            Wt1[n * cH + k] = (unsigned short)f2bf(v);
        } else {
            int j = wi - cH * cH; int n = j >> 8, k = j & 255;  // n in [0,128)
            float v = (n < cCLS) ? Wn2[k * cCLS + n] : Ws2[k * cCLS + (n - cCLS)];
            Wt2[n * cH + k] = (unsigned short)f2bf(v);
        }
    } else {
        const int ti = (b - ABLK - BBLK - WBLK) * 256 + tid;
        if (ti <= cN1) {
            int lo = 0, hi = cE0;
            while (lo < hi) { int mid = (lo + hi) >> 1; if (dst0[mid] < ti) lo = mid + 1; else hi = mid; }
            row0[ti] = lo;
        } else {
            int d = ti - (cN1 + 1);
            if (d <= cN2) {
                int lo = 0, hi = cE1;
                while (lo < hi) { int mid = (lo + hi) >> 1; if (dst1[mid] < d) lo = mid + 1; else hi = mid; }
                row1[d] = lo;
            }
        }
    }
}

// ---- layer-1 aggregation over biased-u8 rows ----
// One wave per dst row: 4 edge slots x 16 chunk lanes (8 B = 8 feats each).
// Bytes stored biased (q+128): accumulate 2 features per u32 as packed u16
// fields with plain adds (no carry: max deg*255 << 65536). Decode = 5 VALU
// per dword instead of 8; acc regs 8 -> 4; bias removed exactly at the end.
__global__ __launch_bounds__(256) void agg_i8(
        const uint2* __restrict__ xq,       // [cN0][16] uint2 (128 biased u8 per row)
        const int* __restrict__ sidx,
        const int* __restrict__ rows,
        unsigned short* __restrict__ nb,    // [num_dst][128] bf16
        int num_dst) {
    const int tid = threadIdx.x, lane = tid & 63;
    const int m = blockIdx.x * 4 + (tid >> 6);
    if (m >= num_dst) return;               // wave-uniform
    const int sub = lane >> 4, t = lane & 15;
    const int e0 = rows[m], e1 = rows[m + 1];

    // packed u16 accumulators: accA={f0,f2} accB={f1,f3} accC={f4,f6} accD={f5,f7}
    unsigned int accA = 0, accB = 0, accC = 0, accD = 0;
    auto addq = [&](uint2 v) {
        accA += v.x & 0x00FF00FFu;
        accB += (v.x >> 8) & 0x00FF00FFu;
        accC += v.y & 0x00FF00FFu;
        accD += (v.y >> 8) & 0x00FF00FFu;
    };

    int base = e0;
    for (; base + 16 <= e1; base += 16) {   // 16 edges/iter, 4 loads in flight
        int sA = sidx[base + sub];
        int sB = sidx[base + 4 + sub];
        int sC = sidx[base + 8 + sub];
        int sD = sidx[base + 12 + sub];
        uint2 vA = xq[(size_t)sA * 16 + t];
        uint2 vB = xq[(size_t)sB * 16 + t];
        uint2 vC = xq[(size_t)sC * 16 + t];
        uint2 vD = xq[(size_t)sD * 16 + t];
        addq(vA); addq(vB); addq(vC); addq(vD);
    }
    for (; base < e1; base += 4) {
        int idx = base + sub;
        if (idx < e1) addq(xq[(size_t)sidx[idx] * 16 + t]);
    }

    accA += __shfl_xor((int)accA, 16, 64); accA += __shfl_xor((int)accA, 32, 64);
    accB += __shfl_xor((int)accB, 16, 64); accB += __shfl_xor((int)accB, 32, 64);
    accC += __shfl_xor((int)accC, 16, 64); accC += __shfl_xor((int)accC, 32, 64);
    accD += __shfl_xor((int)accD, 16, 64); accD += __shfl_xor((int)accD, 32, 64);

    if (sub == 0) {                         // lane t holds feats [t*8, t*8+8)
        const int deg = e1 - e0;
        const float inv  = QSTEP / (float)(deg > 1 ? deg : 1);
        const float bias = 128.0f * (float)deg;
        auto cv = [&](unsigned int field) -> float {
            return ((float)(int)field - bias) * inv;
        };
        float f0 = cv(accA & 0xFFFFu), f2 = cv(accA >> 16);
        float f1 = cv(accB & 0xFFFFu), f3 = cv(accB >> 16);
        float f4 = cv(accC & 0xFFFFu), f6 = cv(accC >> 16);
        float f5 = cv(accD & 0xFFFFu), f7 = cv(accD >> 16);
        uint4 w;
        w.x = f2bf(f0) | (f2bf(f1) << 16);
        w.y = f2bf(f2) | (f2bf(f3) << 16);
        w.z = f2bf(f4) | (f2bf(f5) << 16);
        w.w = f2bf(f6) | (f2bf(f7) << 16);
        ((uint4*)nb)[(size_t)m * 16 + t] = w;
    }
}

// ---- layer-2 aggregation (bf16 zb rows, fp32 accumulate into out) ----
template<int K, bool ACCUM>
__global__ __launch_bounds__(256) void agg_wave(
        const unsigned short* __restrict__ src,
        const int* __restrict__ sidx,
        const int* __restrict__ rows,
        void* __restrict__ outv, int num_dst) {
    constexpr int LPR = K / 8;           // lanes per row
    constexpr int EPW = 64 / LPR;        // edge slots per wave
    const int tid = threadIdx.x;
    const int lane = tid & 63;
    const int m = blockIdx.x * 4 + (tid >> 6);
    if (m >= num_dst) return;
    const int sub = lane / LPR;
    const int t   = lane % LPR;

    const uint4* s4 = (const uint4*)src;
    const int e0 = rows[m], e1 = rows[m + 1];

    float acc[8];
    #pragma unroll
    for (int j = 0; j < 8; ++j) acc[j] = 0.f;
    auto addv = [&](uint4 v) {
        acc[0] += bflo(v.x); acc[1] += bfhi(v.x);
        acc[2] += bflo(v.y); acc[3] += bfhi(v.y);
        acc[4] += bflo(v.z); acc[5] += bfhi(v.z);
        acc[6] += bflo(v.w); acc[7] += bfhi(v.w);
    };

    int base = e0;
    for (; base + 2 * EPW <= e1; base += 2 * EPW) {
        int sA = sidx[base + sub], sB = sidx[base + EPW + sub];
        uint4 vA = s4[(size_t)sA * LPR + t];
        uint4 vB = s4[(size_t)sB * LPR + t];
        addv(vA); addv(vB);
    }
    for (; base < e1; base += EPW) {
        int idx = base + sub;
        if (idx < e1) addv(s4[(size_t)sidx[idx] * LPR + t]);
    }

    #pragma unroll
    for (int j = 0; j < 8; ++j) {
        #pragma unroll
        for (int off = LPR; off < 64; off <<= 1)
            acc[j] += __shfl_xor(acc[j], off, 64);
    }

    if (sub == 0) {
        const int deg = e1 - e0;
        const float inv = 1.0f / (float)(deg > 1 ? deg : 1);
        if (!ACCUM) {
            uint4 o;
            o.x = f2bf(acc[0] * inv) | (f2bf(acc[1] * inv) << 16);
            o.y = f2bf(acc[2] * inv) | (f2bf(acc[3] * inv) << 16);
            o.z = f2bf(acc[4] * inv) | (f2bf(acc[5] * inv) << 16);
            o.w = f2bf(acc[6] * inv) | (f2bf(acc[7] * inv) << 16);
            ((uint4*)outv)[(size_t)m * LPR + t] = o;
        } else {
            float* op = (float*)outv + (size_t)m * K + t * 8;
            float4 o0 = *(float4*)op, o1 = *(float4*)(op + 4);
            o0.x += acc[0] * inv; o0.y += acc[1] * inv;
            o0.z += acc[2] * inv; o0.w += acc[3] * inv;
            o1.x += acc[4] * inv; o1.y += acc[5] * inv;
            o1.z += acc[6] * inv; o1.w += acc[7] * inv;
            *(float4*)op = o0; *(float4*)(op + 4) = o1;
        }
    }
}

// ---- bf16 MFMA GEMM (layer 1): h1 = relu([xb|nb] @ Wt1^T + b1) ----
template<int BM, int BN, int WM, int WN, bool RELU, bool HASBIAS, bool OUTBF16>
__global__ __launch_bounds__(256) void gemm_mfma(
        const unsigned short* __restrict__ A1, int K1,
        const unsigned short* __restrict__ A2, int K2,
        const unsigned short* __restrict__ Bt,
        const float* __restrict__ bias,
        void* __restrict__ Cout, int M, int N) {
    static_assert(2 * WM * 16 == BM && 2 * WN * 16 == BN, "wave tiling");
    __shared__ unsigned short As[BM][40];
    __shared__ unsigned short Bs[BN][40];

    const int tid = threadIdx.x;
    const int m0 = blockIdx.x * BM, n0 = blockIdx.y * BN;
    const int lane = tid & 63, wave = tid >> 6;
    const int wrow = wave >> 1, wcol = wave & 1;
    const int quad = lane >> 4, l16 = lane & 15;
    const int K = K1 + K2;

    f32x4 acc[WM][WN];
    #pragma unroll
    for (int i = 0; i < WM; ++i)
        #pragma unroll
        for (int j = 0; j < WN; ++j)
            acc[i][j] = (f32x4){0.f, 0.f, 0.f, 0.f};

    for (int kb = 0; kb < K; kb += 32) {
        const unsigned short* Ab; int lda, kloc;
        if (kb < K1) { Ab = A1; lda = K1; kloc = kb; }
        else         { Ab = A2; lda = K2; kloc = kb - K1; }

        #pragma unroll
        for (int f = 0; f < (BM * 4) / 256; ++f) {
            int idx = tid + f * 256;
            int row = idx >> 2, q = idx & 3;
            int gm = m0 + row;
            uint4 v = make_uint4(0, 0, 0, 0);
            if (gm < M) v = *(const uint4*)(Ab + (size_t)gm * lda + kloc + q * 8);
            *(uint4*)&As[row][q * 8] = v;
        }
        #pragma unroll
        for (int f = 0; f < (BN * 4) / 256; ++f) {
            int idx = tid + f * 256;
            int row = idx >> 2, q = idx & 3;
            uint4 v = *(const uint4*)(Bt + (size_t)(n0 + row) * K + kb + q * 8);
            *(uint4*)&Bs[row][q * 8] = v;
        }
        __syncthreads();

        bf16x8 a[WM], b[WN];
        #pragma unroll
        for (int i = 0; i < WM; ++i)
            a[i] = *(const bf16x8*)&As[(wrow * WM + i) * 16 + l16][quad * 8];
        #pragma unroll
        for (int j = 0; j < WN; ++j)
            b[j] = *(const bf16x8*)&Bs[(wcol * WN + j) * 16 + l16][quad * 8];
        #pragma unroll
        for (int i = 0; i < WM; ++i)
            #pragma unroll
            for (int j = 0; j < WN; ++j)
                acc[i][j] = __builtin_amdgcn_mfma_f32_16x16x32_bf16(
                    a[i], b[j], acc[i][j], 0, 0, 0);
        __syncthreads();
    }

    float bv[WN];
    #pragma unroll
    for (int j = 0; j < WN; ++j)
        bv[j] = HASBIAS ? bias[n0 + (wcol * WN + j) * 16 + l16] : 0.f;
    #pragma unroll
    for (int i = 0; i < WM; ++i) {
        #pragma unroll
        for (int r = 0; r < 4; ++r) {
            int gm = m0 + (wrow * WM + i) * 16 + quad * 4 + r;
            if (gm >= M) continue;
            #pragma unroll
            for (int j = 0; j < WN; ++j) {
                int gn = n0 + (wcol * WN + j) * 16 + l16;
                float v = acc[i][j][r] + bv[j];
                if (RELU) v = fmaxf(v, 0.f);
                if (OUTBF16)
                    ((unsigned short*)Cout)[(size_t)gm * N + gn] = (unsigned short)f2bf(v);
                else
                    ((float*)Cout)[(size_t)gm * N + gn] = v;
            }
        }
    }
}

// ---- layer-2 merged GEMM: one pass over h1b computing [z | self] ----
__global__ __launch_bounds__(256) void gemm2_split(
        const unsigned short* __restrict__ A,    // h1b [cN1][256]
        const unsigned short* __restrict__ Bt,   // Wt2 [128][256]
        const float* __restrict__ b2,
        unsigned short* __restrict__ zb,         // [cN1][64]
        float* __restrict__ out) {               // [cN2][64]
    __shared__ unsigned short As[128][40];
    __shared__ unsigned short Bs[128][40];
    const int tid = threadIdx.x;
    const int m0 = blockIdx.x * 128;
    const int lane = tid & 63, wave = tid >> 6;
    const int wrow = wave >> 1, wcol = wave & 1;
    const int quad = lane >> 4, l16 = lane & 15;

    f32x4 acc[4][4];
    #pragma unroll
    for (int i = 0; i < 4; ++i)
        #pragma unroll
        for (int j = 0; j < 4; ++j)
            acc[i][j] = (f32x4){0.f, 0.f, 0.f, 0.f};

    for (int kb = 0; kb < cH; kb += 32) {
        #pragma unroll
        for (int f = 0; f < 2; ++f) {
            int idx = tid + f * 256;
            int row = idx >> 2, q = idx & 3;
            int gm = m0 + row;
            uint4 v = make_uint4(0, 0, 0, 0);
            if (gm < cN1) v = *(const uint4*)(A + (size_t)gm * cH + kb + q * 8);
            *(uint4*)&As[row][q * 8] = v;
        }
        #pragma unroll
        for (int f = 0; f < 2; ++f) {
            int idx = tid + f * 256;
            int row = idx >> 2, q = idx & 3;
            uint4 v = *(const uint4*)(Bt + (size_t)row * cH + kb + q * 8);
            *(uint4*)&Bs[row][q * 8] = v;
        }
        __syncthreads();

        bf16x8 a[4], b[4];
        #pragma unroll
        for (int i = 0; i < 4; ++i)
            a[i] = *(const bf16x8*)&As[(wrow * 4 + i) * 16 + l16][quad * 8];
        #pragma unroll
        for (int j = 0; j < 4; ++j)
            b[j] = *(const bf16x8*)&Bs[(wcol * 4 + j) * 16 + l16][quad * 8];
        #pragma unroll
        for (int i = 0; i < 4; ++i)
            #pragma unroll
            for (int j = 0; j < 4; ++j)
                acc[i][j] = __builtin_amdgcn_mfma_f32_16x16x32_bf16(
                    a[i], b[j], acc[i][j], 0, 0, 0);
        __syncthreads();
    }

    if (wcol == 0) {                      // z half -> zb (bf16), all rows
        #pragma unroll
        for (int i = 0; i < 4; ++i) {
            #pragma unroll
            for (int r = 0; r < 4; ++r) {
                int gm = m0 + (wrow * 4 + i) * 16 + quad * 4 + r;
                if (gm >= cN1) continue;
                #pragma unroll
                for (int j = 0; j < 4; ++j) {
                    int gn = j * 16 + l16;
                    zb[(size_t)gm * cCLS + gn] = (unsigned short)f2bf(acc[i][j][r]);
                }
            }
        }
    } else {                              // self half -> out (fp32 + bias), rows < cN2
        float bv[4];
        #pragma unroll
        for (int j = 0; j < 4; ++j) bv[j] = b2[j * 16 + l16];
        #pragma unroll
        for (int i = 0; i < 4; ++i) {
            #pragma unroll
            for (int r = 0; r < 4; ++r) {
                int gm = m0 + (wrow * 4 + i) * 16 + quad * 4 + r;
                if (gm >= cN2) continue;
                #pragma unroll
                for (int j = 0; j < 4; ++j)
                    out[(size_t)gm * cCLS + j * 16 + l16] = acc[i][j][r] + bv[j];
            }
        }
    }
}

extern "C" void kernel_launch(void* const* d_in, const int* in_sizes, int n_in,
                              void* d_out, int out_size, void* d_ws, size_t ws_size,
                              hipStream_t stream) {
    const float* x      = (const float*)d_in[0];
    const int*   src0   = (const int*)d_in[1];
    const int*   dst0   = (const int*)d_in[2];
    const int*   src1   = (const int*)d_in[3];
    const int*   dst1   = (const int*)d_in[4];
    const float* Wself1  = (const float*)d_in[7];
    const float* Wneigh1 = (const float*)d_in[8];
    const float* b1      = (const float*)d_in[9];
    const float* Wself2  = (const float*)d_in[10];
    const float* Wneigh2 = (const float*)d_in[11];
    const float* b2      = (const float*)d_in[12];
    float* out = (float*)d_out;

    // ---- workspace layout (zb aliases xq: xq dead after agg_i8) ----
    char* ws = (char*)d_ws;
    int* row0 = (int*)ws;                          // cN1+1
    int* row1 = row0 + (cN1 + 1);                  // cN2+1
    size_t off = (size_t)((cN1 + 1) + (cN2 + 1)) * sizeof(int);
    off = (off + 1023) & ~(size_t)1023;
    unsigned short* xb = (unsigned short*)(ws + off); off += (size_t)cN1 * cIN * 2;  // 25.6 MB (rows < cN1 only)
    unsigned int*   xq = (unsigned int*)(ws + off);                                   // 25.6 MB
    unsigned short* zb = (unsigned short*)(ws + off); off += (size_t)cN0 * cIN;       // alias
    unsigned short* nb  = (unsigned short*)(ws + off); off += (size_t)cN1 * cIN * 2; // 25.6 MB
    unsigned short* h1b = (unsigned short*)(ws + off); off += (size_t)cN1 * cH * 2;  // 51.2 MB
    unsigned short* Wt1 = (unsigned short*)(ws + off); off += (size_t)cH * cH * 2;
    unsigned short* Wt2 = (unsigned short*)(ws + off); off += (size_t)2 * cCLS * cH * 2;

    // 1. all preprocessing in one dispatch
    prep<<<ABLK + BBLK + WBLK + RBLK, 256, 0, stream>>>(
        x, Wself1, Wneigh1, Wneigh2, Wself2, dst0, dst1,
        xb, xq, Wt1, Wt2, row0, row1);

    // 2. layer-1 aggregation (biased-u8 gather, packed-u16 accumulate)
    agg_i8<<<(cN1 + 3) / 4, 256, 0, stream>>>(
        (const uint2*)xq, src0, row0, nb, cN1);

    // 3. layer-1 GEMM: h1b = relu([xb|nb] @ Wt1^T + b1)
    gemm_mfma<128, 128, 4, 4, true, true, true>
        <<<dim3((cN1 + 127) / 128, cH / 128), 256, 0, stream>>>(
        xb, cIN, nb, cIN, Wt1, b1, h1b, cN1, cH);

    // 4. layer-2 merged GEMM: zb = h1b @ Wn2 ; out = h1b[:cN2] @ Ws2 + b2
    gemm2_split<<<(cN1 + 127) / 128, 256, 0, stream>>>(h1b, Wt2, b2, zb, out);

    // 5. layer-2 aggregation: out += segmean(zb)
    agg_wave<cCLS, true><<<(cN2 + 3) / 4, 256, 0, stream>>>(
        zb, src1, row1, out, cN2);
}

// Round 2
// 331.429 us; speedup vs baseline: 1.0308x; 1.0106x over previous
//
#include <hip/hip_runtime.h>

// Problem constants (fixed by the reference file)
constexpr int cN0  = 200000;   // num src nodes
constexpr int cN1  = 100000;   // num_dst layer 1
constexpr int cN2  = 50000;    // num_dst layer 2
constexpr int cE0  = 1600000;
constexpr int cE1  = 800000;
constexpr int cIN  = 128;      // IN_F
constexpr int cH   = 256;      // H_F
constexpr int cCLS = 64;       // N_CLS

// int8 quantization of x (values ~N(0,1); clip at +-6 sigma)
constexpr float QSTEP = 6.0f / 127.0f;
constexpr float QINV  = 127.0f / 6.0f;

using bf16x8 = __attribute__((ext_vector_type(8))) short;   // 8 bf16 = 4 VGPRs
using f32x4  = __attribute__((ext_vector_type(4))) float;

__device__ __forceinline__ float bflo(unsigned int u) {
    union { unsigned int i; float f; } v; v.i = u << 16; return v.f;
}
__device__ __forceinline__ float bfhi(unsigned int u) {
    union { unsigned int i; float f; } v; v.i = u & 0xFFFF0000u; return v.f;
}
__device__ __forceinline__ unsigned int f2bf(float f) {   // RNE
    union { float f; unsigned int i; } v; v.f = f;
    return (v.i + 0x7FFFu + ((v.i >> 16) & 1u)) >> 16;
}

// ---- prep: one kernel for all preprocessing ----
// Region Q: quantize all of x -> biased u8 (no bf16 copy; gemm1 reads x fp32).
// Region W: weight transposes.  Region R: CSR row-pointer binary searches.
constexpr int PV   = 8;                              // float4 per thread (ILP)
constexpr int QF4  = cN0 * cIN / 4;                  // 6,400,000 float4
constexpr int QBLK = QF4 / (256 * PV);               // 3125 (exact)
constexpr int WCNT = cH * cH + 2 * cCLS * cH;        // 98304
constexpr int WBLK = WCNT / 256;                     // 384
constexpr int RCNT = (cN1 + 1) + (cN2 + 1);          // 150002
constexpr int RBLK = (RCNT + 255) / 256;             // 586

__global__ __launch_bounds__(256) void prep(
        const float* __restrict__ x,
        const float* __restrict__ Ws1, const float* __restrict__ Wn1,
        const float* __restrict__ Wn2, const float* __restrict__ Ws2,
        const int* __restrict__ dst0, const int* __restrict__ dst1,
        unsigned int* __restrict__ xq,
        unsigned short* __restrict__ Wt1, unsigned short* __restrict__ Wt2,
        int* __restrict__ row0, int* __restrict__ row1) {
    const int b = blockIdx.x, tid = threadIdx.x;
    if (b < QBLK) {
        const int base = b * 256 * PV + tid;
        const float4* xp = (const float4*)x;

        float4 v[PV];
        #pragma unroll
        for (int j = 0; j < PV; ++j)             // 8 independent loads in flight
            v[j] = xp[base + j * 256];
        auto q8b = [](float f) -> unsigned int { // biased: q+128 in [1,255]
            int q = __float2int_rn(f * QINV);
            q = q > 127 ? 127 : (q < -127 ? -127 : q);
            return (unsigned int)(q + 128);
        };
        #pragma unroll
        for (int j = 0; j < PV; ++j) {
            float4 a = v[j];
            unsigned int d = q8b(a.x) | (q8b(a.y) << 8) |
                             (q8b(a.z) << 16) | (q8b(a.w) << 24);
            xq[base + j * 256] = d;
        }
    } else if (b < QBLK + WBLK) {
        const int wi = (b - QBLK) * 256 + tid;
        if (wi < cH * cH) {
            int n = wi >> 8, k = wi & 255;
            float v = (k < cIN) ? Ws1[k * cH + n] : Wn1[(k - cIN) * cH + n];
            Wt1[n * cH + k] = (unsigned short)f2bf(v);
        } else {
            int j = wi - cH * cH; int n = j >> 8, k = j & 255;  // n in [0,128)
            float v = (n < cCLS) ? Wn2[k * cCLS + n] : Ws2[k * cCLS + (n - cCLS)];
            Wt2[n * cH + k] = (unsigned short)f2bf(v);
        }
    } else {
        const int ti = (b - QBLK - WBLK) * 256 + tid;
        if (ti <= cN1) {
            int lo = 0, hi = cE0;
            while (lo < hi) { int mid = (lo + hi) >> 1; if (dst0[mid] < ti) lo = mid + 1; else hi = mid; }
            row0[ti] = lo;
        } else {
            int d = ti - (cN1 + 1);
            if (d <= cN2) {
                int lo = 0, hi = cE1;
                while (lo < hi) { int mid = (lo + hi) >> 1; if (dst1[mid] < d) lo = mid + 1; else hi = mid; }
                row1[d] = lo;
            }
        }
    }
}

// ---- layer-1 aggregation over biased-u8 rows ----
// One wave per dst row: 4 edge slots x 16 chunk lanes (8 B = 8 feats each).
// Flat clamped loop: EVERY iteration issues 4 sidx loads + 16 row-gathers in
// flight (short rows pipeline like long ones); invalid slots are clamped to
// e0 and masked to zero before the packed-u16 accumulate (no carry possible:
// max deg*255 << 65536). Bias (q+128) removed exactly at the end.
__global__ __launch_bounds__(256) void agg_i8(
        const uint2* __restrict__ xq,       // [cN0][16] uint2 (128 biased u8 per row)
        const int* __restrict__ sidx,
        const int* __restrict__ rows,
        unsigned short* __restrict__ nb,    // [num_dst][128] bf16
        int num_dst) {
    const int tid = threadIdx.x, lane = tid & 63;
    const int m = blockIdx.x * 4 + (tid >> 6);
    if (m >= num_dst) return;               // wave-uniform
    const int sub = lane >> 4, t = lane & 15;
    const int e0 = rows[m], e1 = rows[m + 1];

    // packed u16 accumulators: accA={f0,f2} accB={f1,f3} accC={f4,f6} accD={f5,f7}
    unsigned int accA = 0, accB = 0, accC = 0, accD = 0;

    for (int base = e0; base < e1; base += 16) {
        int s[4]; bool val[4];
        #pragma unroll
        for (int k = 0; k < 4; ++k) {
            int ei = base + k * 4 + sub;
            val[k] = ei < e1;
            s[k] = sidx[val[k] ? ei : e0];   // e0 valid whenever loop runs
        }
        uint2 v[4];
        #pragma unroll
        for (int k = 0; k < 4; ++k)
            v[k] = xq[(size_t)s[k] * 16 + t];
        #pragma unroll
        for (int k = 0; k < 4; ++k) {
            uint2 w = val[k] ? v[k] : make_uint2(0u, 0u);
            accA += w.x & 0x00FF00FFu;
            accB += (w.x >> 8) & 0x00FF00FFu;
            accC += w.y & 0x00FF00FFu;
            accD += (w.y >> 8) & 0x00FF00FFu;
        }
    }

    accA += __shfl_xor((int)accA, 16, 64); accA += __shfl_xor((int)accA, 32, 64);
    accB += __shfl_xor((int)accB, 16, 64); accB += __shfl_xor((int)accB, 32, 64);
    accC += __shfl_xor((int)accC, 16, 64); accC += __shfl_xor((int)accC, 32, 64);
    accD += __shfl_xor((int)accD, 16, 64); accD += __shfl_xor((int)accD, 32, 64);

    if (sub == 0) {                         // lane t holds feats [t*8, t*8+8)
        const int deg = e1 - e0;
        const float inv  = QSTEP / (float)(deg > 1 ? deg : 1);
        const float bias = 128.0f * (float)deg;
        auto cv = [&](unsigned int field) -> float {
            return ((float)(int)field - bias) * inv;
        };
        float f0 = cv(accA & 0xFFFFu), f2 = cv(accA >> 16);
        float f1 = cv(accB & 0xFFFFu), f3 = cv(accB >> 16);
        float f4 = cv(accC & 0xFFFFu), f6 = cv(accC >> 16);
        float f5 = cv(accD & 0xFFFFu), f7 = cv(accD >> 16);
        uint4 w;
        w.x = f2bf(f0) | (f2bf(f1) << 16);
        w.y = f2bf(f2) | (f2bf(f3) << 16);
        w.z = f2bf(f4) | (f2bf(f5) << 16);
        w.w = f2bf(f6) | (f2bf(f7) << 16);
        ((uint4*)nb)[(size_t)m * 16 + t] = w;
    }
}

// ---- layer-2 aggregation (bf16 zb rows, fp32 accumulate into out) ----
template<int K, bool ACCUM>
__global__ __launch_bounds__(256) void agg_wave(
        const unsigned short* __restrict__ src,
        const int* __restrict__ sidx,
        const int* __restrict__ rows,
        void* __restrict__ outv, int num_dst) {
    constexpr int LPR = K / 8;           // lanes per row
    constexpr int EPW = 64 / LPR;        // edge slots per wave
    const int tid = threadIdx.x;
    const int lane = tid & 63;
    const int m = blockIdx.x * 4 + (tid >> 6);
    if (m >= num_dst) return;
    const int sub = lane / LPR;
    const int t   = lane % LPR;

    const uint4* s4 = (const uint4*)src;
    const int e0 = rows[m], e1 = rows[m + 1];

    float acc[8];
    #pragma unroll
    for (int j = 0; j < 8; ++j) acc[j] = 0.f;
    auto addv = [&](uint4 v) {
        acc[0] += bflo(v.x); acc[1] += bfhi(v.x);
        acc[2] += bflo(v.y); acc[3] += bfhi(v.y);
        acc[4] += bflo(v.z); acc[5] += bfhi(v.z);
        acc[6] += bflo(v.w); acc[7] += bfhi(v.w);
    };

    int base = e0;
    for (; base + 2 * EPW <= e1; base += 2 * EPW) {
        int sA = sidx[base + sub], sB = sidx[base + EPW + sub];
        uint4 vA = s4[(size_t)sA * LPR + t];
        uint4 vB = s4[(size_t)sB * LPR + t];
        addv(vA); addv(vB);
    }
    for (; base < e1; base += EPW) {
        int idx = base + sub;
        if (idx < e1) addv(s4[(size_t)sidx[idx] * LPR + t]);
    }

    #pragma unroll
    for (int j = 0; j < 8; ++j) {
        #pragma unroll
        for (int off = LPR; off < 64; off <<= 1)
            acc[j] += __shfl_xor(acc[j], off, 64);
    }

    if (sub == 0) {
        const int deg = e1 - e0;
        const float inv = 1.0f / (float)(deg > 1 ? deg : 1);
        if (!ACCUM) {
            uint4 o;
            o.x = f2bf(acc[0] * inv) | (f2bf(acc[1] * inv) << 16);
            o.y = f2bf(acc[2] * inv) | (f2bf(acc[3] * inv) << 16);
            o.z = f2bf(acc[4] * inv) | (f2bf(acc[5] * inv) << 16);
            o.w = f2bf(acc[6] * inv) | (f2bf(acc[7] * inv) << 16);
            ((uint4*)outv)[(size_t)m * LPR + t] = o;
        } else {
            float* op = (float*)outv + (size_t)m * K + t * 8;
            float4 o0 = *(float4*)op, o1 = *(float4*)(op + 4);
            o0.x += acc[0] * inv; o0.y += acc[1] * inv;
            o0.z += acc[2] * inv; o0.w += acc[3] * inv;
            o1.x += acc[4] * inv; o1.y += acc[5] * inv;
            o1.z += acc[6] * inv; o1.w += acc[7] * inv;
            *(float4*)op = o0; *(float4*)(op + 4) = o1;
        }
    }
}

// ---- layer-1 fused GEMM: h1b = relu([f2bf(x) | nb] @ Wt1^T + b1) ----
// 512 threads, BM=128 x BN=256 (full N in one pass; A read once).
// A-operand staged from fp32 x (k<128, converted to bf16 in staging -- same
// f2bf as before, identical numerics) or from nb (k>=128, already bf16).
__global__ __launch_bounds__(512) void gemm1_fused(
        const float* __restrict__ X,            // [cN1][128] fp32 (rows < cN1 of x)
        const unsigned short* __restrict__ NB,  // [cN1][128] bf16
        const unsigned short* __restrict__ Bt,  // Wt1 [256][256] bf16
        const float* __restrict__ bias,
        unsigned short* __restrict__ C) {       // h1b [cN1][256] bf16
    __shared__ unsigned short As[128][40];
    __shared__ unsigned short Bs[256][40];

    const int tid = threadIdx.x;
    const int m0 = blockIdx.x * 128;
    const int lane = tid & 63, wave = tid >> 6;   // 8 waves
    const int wrow = wave >> 2, wcol = wave & 3;  // 2 x 4 wave grid
    const int quad = lane >> 4, l16 = lane & 15;

    f32x4 acc[4][4];
    #pragma unroll
    for (int i = 0; i < 4; ++i)
        #pragma unroll
        for (int j = 0; j < 4; ++j)
            acc[i][j] = (f32x4){0.f, 0.f, 0.f, 0.f};

    const int arow = tid >> 2, aq = tid & 3;      // 128 rows x 4 chunks
    const int gma  = m0 + arow;

    for (int kb = 0; kb < cH; kb += 32) {
        // ---- A tile: 128 x 32 bf16 ----
        if (kb < cIN) {
            float4 a0 = {0,0,0,0}, a1 = {0,0,0,0};
            if (gma < cN1) {
                const float4* p = (const float4*)(X + (size_t)gma * cIN + kb + aq * 8);
                a0 = p[0]; a1 = p[1];
            }
            uint4 v;
            v.x = f2bf(a0.x) | (f2bf(a0.y) << 16);
            v.y = f2bf(a0.z) | (f2bf(a0.w) << 16);
            v.z = f2bf(a1.x) | (f2bf(a1.y) << 16);
            v.w = f2bf(a1.z) | (f2bf(a1.w) << 16);
            *(uint4*)&As[arow][aq * 8] = v;
        } else {
            uint4 v = make_uint4(0, 0, 0, 0);
            if (gma < cN1)
                v = *(const uint4*)(NB + (size_t)gma * cIN + (kb - cIN) + aq * 8);
            *(uint4*)&As[arow][aq * 8] = v;
        }
        // ---- B tile: 256 x 32 bf16 (1024 uint4, 2 per thread) ----
        #pragma unroll
        for (int f = 0; f < 2; ++f) {
            int idx = tid + f * 512;
            int row = idx >> 2, q = idx & 3;
            uint4 v = *(const uint4*)(Bt + (size_t)row * cH + kb + q * 8);
            *(uint4*)&Bs[row][q * 8] = v;
        }
        __syncthreads();

        bf16x8 a[4], b[4];
        #pragma unroll
        for (int i = 0; i < 4; ++i)
            a[i] = *(const bf16x8*)&As[wrow * 64 + i * 16 + l16][quad * 8];
        #pragma unroll
        for (int j = 0; j < 4; ++j)
            b[j] = *(const bf16x8*)&Bs[wcol * 64 + j * 16 + l16][quad * 8];
        #pragma unroll
        for (int i = 0; i < 4; ++i)
            #pragma unroll
            for (int j = 0; j < 4; ++j)
                acc[i][j] = __builtin_amdgcn_mfma_f32_16x16x32_bf16(
                    a[i], b[j], acc[i][j], 0, 0, 0);
        __syncthreads();
    }

    float bv[4];
    #pragma unroll
    for (int j = 0; j < 4; ++j)
        bv[j] = bias[wcol * 64 + j * 16 + l16];
    #pragma unroll
    for (int i = 0; i < 4; ++i) {
        #pragma unroll
        for (int r = 0; r < 4; ++r) {
            int gm = m0 + wrow * 64 + i * 16 + quad * 4 + r;
            if (gm >= cN1) continue;
            #pragma unroll
            for (int j = 0; j < 4; ++j) {
                int gn = wcol * 64 + j * 16 + l16;
                float v = acc[i][j][r] + bv[j];
                v = fmaxf(v, 0.f);
                C[(size_t)gm * cH + gn] = (unsigned short)f2bf(v);
            }
        }
    }
}

// ---- layer-2 merged GEMM: one pass over h1b computing [z | self] ----
__global__ __launch_bounds__(256) void gemm2_split(
        const unsigned short* __restrict__ A,    // h1b [cN1][256]
        const unsigned short* __restrict__ Bt,   // Wt2 [128][256]
        const float* __restrict__ b2,
        unsigned short* __restrict__ zb,         // [cN1][64]
        float* __restrict__ out) {               // [cN2][64]
    __shared__ unsigned short As[128][40];
    __shared__ unsigned short Bs[128][40];
    const int tid = threadIdx.x;
    const int m0 = blockIdx.x * 128;
    const int lane = tid & 63, wave = tid >> 6;
    const int wrow = wave >> 1, wcol = wave & 1;
    const int quad = lane >> 4, l16 = lane & 15;

    f32x4 acc[4][4];
    #pragma unroll
    for (int i = 0; i < 4; ++i)
        #pragma unroll
        for (int j = 0; j < 4; ++j)
            acc[i][j] = (f32x4){0.f, 0.f, 0.f, 0.f};

    for (int kb = 0; kb < cH; kb += 32) {
        #pragma unroll
        for (int f = 0; f < 2; ++f) {
            int idx = tid + f * 256;
            int row = idx >> 2, q = idx & 3;
            int gm = m0 + row;
            uint4 v = make_uint4(0, 0, 0, 0);
            if (gm < cN1) v = *(const uint4*)(A + (size_t)gm * cH + kb + q * 8);
            *(uint4*)&As[row][q * 8] = v;
        }
        #pragma unroll
        for (int f = 0; f < 2; ++f) {
            int idx = tid + f * 256;
            int row = idx >> 2, q = idx & 3;
            uint4 v = *(const uint4*)(Bt + (size_t)row * cH + kb + q * 8);
            *(uint4*)&Bs[row][q * 8] = v;
        }
        __syncthreads();

        bf16x8 a[4], b[4];
        #pragma unroll
        for (int i = 0; i < 4; ++i)
            a[i] = *(const bf16x8*)&As[(wrow * 4 + i) * 16 + l16][quad * 8];
        #pragma unroll
        for (int j = 0; j < 4; ++j)
            b[j] = *(const bf16x8*)&Bs[(wcol * 4 + j) * 16 + l16][quad * 8];
        #pragma unroll
        for (int i = 0; i < 4; ++i)
            #pragma unroll
            for (int j = 0; j < 4; ++j)
                acc[i][j] = __builtin_amdgcn_mfma_f32_16x16x32_bf16(
                    a[i], b[j], acc[i][j], 0, 0, 0);
        __syncthreads();
    }

    if (wcol == 0) {                      // z half -> zb (bf16), all rows
        #pragma unroll
        for (int i = 0; i < 4; ++i) {
            #pragma unroll
            for (int r = 0; r < 4; ++r) {
                int gm = m0 + (wrow * 4 + i) * 16 + quad * 4 + r;
                if (gm >= cN1) continue;
                #pragma unroll
                for (int j = 0; j < 4; ++j) {
                    int gn = j * 16 + l16;
                    zb[(size_t)gm * cCLS + gn] = (unsigned short)f2bf(acc[i][j][r]);
                }
            }
        }
    } else {                              // self half -> out (fp32 + bias), rows < cN2
        float bv[4];
        #pragma unroll
        for (int j = 0; j < 4; ++j) bv[j] = b2[j * 16 + l16];
        #pragma unroll
        for (int i = 0; i < 4; ++i) {
            #pragma unroll
            for (int r = 0; r < 4; ++r) {
                int gm = m0 + (wrow * 4 + i) * 16 + quad * 4 + r;
                if (gm >= cN2) continue;
                #pragma unroll
                for (int j = 0; j < 4; ++j)
                    out[(size_t)gm * cCLS + j * 16 + l16] = acc[i][j][r] + bv[j];
            }
        }
    }
}

extern "C" void kernel_launch(void* const* d_in, const int* in_sizes, int n_in,
                              void* d_out, int out_size, void* d_ws, size_t ws_size,
                              hipStream_t stream) {
    const float* x      = (const float*)d_in[0];
    const int*   src0   = (const int*)d_in[1];
    const int*   dst0   = (const int*)d_in[2];
    const int*   src1   = (const int*)d_in[3];
    const int*   dst1   = (const int*)d_in[4];
    const float* Wself1  = (const float*)d_in[7];
    const float* Wneigh1 = (const float*)d_in[8];
    const float* b1      = (const float*)d_in[9];
    const float* Wself2  = (const float*)d_in[10];
    const float* Wneigh2 = (const float*)d_in[11];
    const float* b2      = (const float*)d_in[12];
    float* out = (float*)d_out;

    // ---- workspace layout (zb aliases xq: xq dead after agg_i8) ----
    char* ws = (char*)d_ws;
    int* row0 = (int*)ws;                          // cN1+1
    int* row1 = row0 + (cN1 + 1);                  // cN2+1
    size_t off = (size_t)((cN1 + 1) + (cN2 + 1)) * sizeof(int);
    off = (off + 1023) & ~(size_t)1023;
    unsigned int*   xq = (unsigned int*)(ws + off);                                   // 25.6 MB
    unsigned short* zb = (unsigned short*)(ws + off); off += (size_t)cN0 * cIN;       // alias (12.8 MB used)
    unsigned short* nb  = (unsigned short*)(ws + off); off += (size_t)cN1 * cIN * 2; // 25.6 MB
    unsigned short* h1b = (unsigned short*)(ws + off); off += (size_t)cN1 * cH * 2;  // 51.2 MB
    unsigned short* Wt1 = (unsigned short*)(ws + off); off += (size_t)cH * cH * 2;
    unsigned short* Wt2 = (unsigned short*)(ws + off); off += (size_t)2 * cCLS * cH * 2;

    // 1. all preprocessing in one dispatch
    prep<<<QBLK + WBLK + RBLK, 256, 0, stream>>>(
        x, Wself1, Wneigh1, Wneigh2, Wself2, dst0, dst1,
        xq, Wt1, Wt2, row0, row1);

    // 2. layer-1 aggregation (biased-u8 gather, packed-u16 accumulate)
    agg_i8<<<(cN1 + 3) / 4, 256, 0, stream>>>(
        (const uint2*)xq, src0, row0, nb, cN1);

    // 3. layer-1 fused GEMM: h1b = relu([f2bf(x)|nb] @ Wt1^T + b1)
    gemm1_fused<<<(cN1 + 127) / 128, 512, 0, stream>>>(
        x, nb, Wt1, b1, h1b);

    // 4. layer-2 merged GEMM: zb = h1b @ Wn2 ; out = h1b[:cN2] @ Ws2 + b2
    gemm2_split<<<(cN1 + 127) / 128, 256, 0, stream>>>(h1b, Wt2, b2, zb, out);

    // 5. layer-2 aggregation: out += segmean(zb)
    agg_wave<cCLS, true><<<(cN2 + 3) / 4, 256, 0, stream>>>(
        zb, src1, row1, out, cN2);
}

// Round 3
// 325.420 us; speedup vs baseline: 1.0498x; 1.0185x over previous
//
#include <hip/hip_runtime.h>

// Problem constants (fixed by the reference file)
constexpr int cN0  = 200000;   // num src nodes
constexpr int cN1  = 100000;   // num_dst layer 1
constexpr int cN2  = 50000;    // num_dst layer 2
constexpr int cE0  = 1600000;
constexpr int cE1  = 800000;
constexpr int cIN  = 128;      // IN_F
constexpr int cH   = 256;      // H_F
constexpr int cCLS = 64;       // N_CLS

// int8 quantization of x (values ~N(0,1); clip at +-6 sigma)
constexpr float QSTEP = 6.0f / 127.0f;
constexpr float QINV  = 127.0f / 6.0f;

using bf16x8 = __attribute__((ext_vector_type(8))) short;   // 8 bf16 = 4 VGPRs
using f32x4  = __attribute__((ext_vector_type(4))) float;

__device__ __forceinline__ float bflo(unsigned int u) {
    union { unsigned int i; float f; } v; v.i = u << 16; return v.f;
}
__device__ __forceinline__ float bfhi(unsigned int u) {
    union { unsigned int i; float f; } v; v.i = u & 0xFFFF0000u; return v.f;
}
__device__ __forceinline__ unsigned int f2bf(float f) {   // RNE
    union { float f; unsigned int i; } v; v.f = f;
    return (v.i + 0x7FFFu + ((v.i >> 16) & 1u)) >> 16;
}

// ---- prep: one kernel for all preprocessing ----
// Region R0/R1: CSR row-pointer build by linear scatter over sorted dst
//   (replaces binary search: no dependent-load chains; dispatched FIRST).
// Region W: weight transposes.
// Region Q: quantize all of x -> biased u8 (gemm reads x fp32 directly).
constexpr int R0T  = cE0 / 4;                        // 400000 threads (4 edges each)
constexpr int R0B  = (R0T + 255) / 256;              // 1563
constexpr int R1T  = cE1 / 4;                        // 200000
constexpr int R1B  = (R1T + 255) / 256;              // 782
constexpr int WCNT = cH * cH + 2 * cCLS * cH;        // 98304
constexpr int WBLK = WCNT / 256;                     // 384
constexpr int PV   = 8;                              // float4 per thread (ILP)
constexpr int QF4  = cN0 * cIN / 4;                  // 6,400,000 float4
constexpr int QBLK = QF4 / (256 * PV);               // 3125 (exact)

__global__ __launch_bounds__(256) void prep(
        const float* __restrict__ x,
        const float* __restrict__ Ws1, const float* __restrict__ Wn1,
        const float* __restrict__ Wn2, const float* __restrict__ Ws2,
        const int* __restrict__ dst0, const int* __restrict__ dst1,
        unsigned int* __restrict__ xq,
        unsigned short* __restrict__ Wt1, unsigned short* __restrict__ Wt2,
        int* __restrict__ row0, int* __restrict__ row1) {
    const int b = blockIdx.x, tid = threadIdx.x;
    if (b < R0B) {
        const int t = b * 256 + tid;
        if (t < R0T) {
            const int e = t * 4;
            int4 cur = *(const int4*)(dst0 + e);
            int prev = (e == 0) ? -1 : dst0[e - 1];
            for (int d = prev + 1;  d <= cur.x; ++d) row0[d] = e;
            for (int d = cur.x + 1; d <= cur.y; ++d) row0[d] = e + 1;
            for (int d = cur.y + 1; d <= cur.z; ++d) row0[d] = e + 2;
            for (int d = cur.z + 1; d <= cur.w; ++d) row0[d] = e + 3;
            if (e + 4 == cE0)
                for (int d = cur.w + 1; d <= cN1; ++d) row0[d] = cE0;
        }
    } else if (b < R0B + R1B) {
        const int t = (b - R0B) * 256 + tid;
        if (t < R1T) {
            const int e = t * 4;
            int4 cur = *(const int4*)(dst1 + e);
            int prev = (e == 0) ? -1 : dst1[e - 1];
            for (int d = prev + 1;  d <= cur.x; ++d) row1[d] = e;
            for (int d = cur.x + 1; d <= cur.y; ++d) row1[d] = e + 1;
            for (int d = cur.y + 1; d <= cur.z; ++d) row1[d] = e + 2;
            for (int d = cur.z + 1; d <= cur.w; ++d) row1[d] = e + 3;
            if (e + 4 == cE1)
                for (int d = cur.w + 1; d <= cN2; ++d) row1[d] = cE1;
        }
    } else if (b < R0B + R1B + WBLK) {
        const int wi = (b - R0B - R1B) * 256 + tid;
        if (wi < cH * cH) {
            int n = wi >> 8, k = wi & 255;
            float v = (k < cIN) ? Ws1[k * cH + n] : Wn1[(k - cIN) * cH + n];
            Wt1[n * cH + k] = (unsigned short)f2bf(v);
        } else {
            int j = wi - cH * cH; int n = j >> 8, k = j & 255;  // n in [0,128)
            float v = (n < cCLS) ? Wn2[k * cCLS + n] : Ws2[k * cCLS + (n - cCLS)];
            Wt2[n * cH + k] = (unsigned short)f2bf(v);
        }
    } else {
        const int qb = b - (R0B + R1B + WBLK);
        const int base = qb * 256 * PV + tid;
        const float4* xp = (const float4*)x;

        float4 v[PV];
        #pragma unroll
        for (int j = 0; j < PV; ++j)             // 8 independent loads in flight
            v[j] = xp[base + j * 256];
        auto q8b = [](float f) -> unsigned int { // biased: q+128 in [1,255]
            int q = __float2int_rn(f * QINV);
            q = q > 127 ? 127 : (q < -127 ? -127 : q);
            return (unsigned int)(q + 128);
        };
        #pragma unroll
        for (int j = 0; j < PV; ++j) {
            float4 a = v[j];
            unsigned int d = q8b(a.x) | (q8b(a.y) << 8) |
                             (q8b(a.z) << 16) | (q8b(a.w) << 24);
            xq[base + j * 256] = d;
        }
    }
}

// ---- layer-1 aggregation over biased-u8 rows ----
// One wave per dst row: 4 edge slots x 16 chunk lanes (8 B = 8 feats each).
// Flat clamped loop: EVERY iteration issues 4 sidx loads + 16 row-gathers in
// flight; invalid slots are clamped to e0 and masked to zero before the
// packed-u16 accumulate (no carry possible: max deg*255 << 65536).
__global__ __launch_bounds__(256) void agg_i8(
        const uint2* __restrict__ xq,       // [cN0][16] uint2 (128 biased u8 per row)
        const int* __restrict__ sidx,
        const int* __restrict__ rows,
        unsigned short* __restrict__ nb,    // [num_dst][128] bf16
        int num_dst) {
    const int tid = threadIdx.x, lane = tid & 63;
    const int m = blockIdx.x * 4 + (tid >> 6);
    if (m >= num_dst) return;               // wave-uniform
    const int sub = lane >> 4, t = lane & 15;
    const int e0 = rows[m], e1 = rows[m + 1];

    // packed u16 accumulators: accA={f0,f2} accB={f1,f3} accC={f4,f6} accD={f5,f7}
    unsigned int accA = 0, accB = 0, accC = 0, accD = 0;

    for (int base = e0; base < e1; base += 16) {
        int s[4]; bool val[4];
        #pragma unroll
        for (int k = 0; k < 4; ++k) {
            int ei = base + k * 4 + sub;
            val[k] = ei < e1;
            s[k] = sidx[val[k] ? ei : e0];   // e0 valid whenever loop runs
        }
        uint2 v[4];
        #pragma unroll
        for (int k = 0; k < 4; ++k)
            v[k] = xq[(size_t)s[k] * 16 + t];
        #pragma unroll
        for (int k = 0; k < 4; ++k) {
            uint2 w = val[k] ? v[k] : make_uint2(0u, 0u);
            accA += w.x & 0x00FF00FFu;
            accB += (w.x >> 8) & 0x00FF00FFu;
            accC += w.y & 0x00FF00FFu;
            accD += (w.y >> 8) & 0x00FF00FFu;
        }
    }

    accA += __shfl_xor((int)accA, 16, 64); accA += __shfl_xor((int)accA, 32, 64);
    accB += __shfl_xor((int)accB, 16, 64); accB += __shfl_xor((int)accB, 32, 64);
    accC += __shfl_xor((int)accC, 16, 64); accC += __shfl_xor((int)accC, 32, 64);
    accD += __shfl_xor((int)accD, 16, 64); accD += __shfl_xor((int)accD, 32, 64);

    if (sub == 0) {                         // lane t holds feats [t*8, t*8+8)
        const int deg = e1 - e0;
        const float inv  = QSTEP / (float)(deg > 1 ? deg : 1);
        const float bias = 128.0f * (float)deg;
        auto cv = [&](unsigned int field) -> float {
            return ((float)(int)field - bias) * inv;
        };
        float f0 = cv(accA & 0xFFFFu), f2 = cv(accA >> 16);
        float f1 = cv(accB & 0xFFFFu), f3 = cv(accB >> 16);
        float f4 = cv(accC & 0xFFFFu), f6 = cv(accC >> 16);
        float f5 = cv(accD & 0xFFFFu), f7 = cv(accD >> 16);
        uint4 w;
        w.x = f2bf(f0) | (f2bf(f1) << 16);
        w.y = f2bf(f2) | (f2bf(f3) << 16);
        w.z = f2bf(f4) | (f2bf(f5) << 16);
        w.w = f2bf(f6) | (f2bf(f7) << 16);
        ((uint4*)nb)[(size_t)m * 16 + t] = w;
    }
}

// ---- layer-2 aggregation (bf16 zb rows, fp32 accumulate into out) ----
template<int K, bool ACCUM>
__global__ __launch_bounds__(256) void agg_wave(
        const unsigned short* __restrict__ src,
        const int* __restrict__ sidx,
        const int* __restrict__ rows,
        void* __restrict__ outv, int num_dst) {
    constexpr int LPR = K / 8;           // lanes per row
    constexpr int EPW = 64 / LPR;        // edge slots per wave
    const int tid = threadIdx.x;
    const int lane = tid & 63;
    const int m = blockIdx.x * 4 + (tid >> 6);
    if (m >= num_dst) return;
    const int sub = lane / LPR;
    const int t   = lane % LPR;

    const uint4* s4 = (const uint4*)src;
    const int e0 = rows[m], e1 = rows[m + 1];

    float acc[8];
    #pragma unroll
    for (int j = 0; j < 8; ++j) acc[j] = 0.f;
    auto addv = [&](uint4 v) {
        acc[0] += bflo(v.x); acc[1] += bfhi(v.x);
        acc[2] += bflo(v.y); acc[3] += bfhi(v.y);
        acc[4] += bflo(v.z); acc[5] += bfhi(v.z);
        acc[6] += bflo(v.w); acc[7] += bfhi(v.w);
    };

    int base = e0;
    for (; base + 2 * EPW <= e1; base += 2 * EPW) {
        int sA = sidx[base + sub], sB = sidx[base + EPW + sub];
        uint4 vA = s4[(size_t)sA * LPR + t];
        uint4 vB = s4[(size_t)sB * LPR + t];
        addv(vA); addv(vB);
    }
    for (; base < e1; base += EPW) {
        int idx = base + sub;
        if (idx < e1) addv(s4[(size_t)sidx[idx] * LPR + t]);
    }

    #pragma unroll
    for (int j = 0; j < 8; ++j) {
        #pragma unroll
        for (int off = LPR; off < 64; off <<= 1)
            acc[j] += __shfl_xor(acc[j], off, 64);
    }

    if (sub == 0) {
        const int deg = e1 - e0;
        const float inv = 1.0f / (float)(deg > 1 ? deg : 1);
        if (!ACCUM) {
            uint4 o;
            o.x = f2bf(acc[0] * inv) | (f2bf(acc[1] * inv) << 16);
            o.y = f2bf(acc[2] * inv) | (f2bf(acc[3] * inv) << 16);
            o.z = f2bf(acc[4] * inv) | (f2bf(acc[5] * inv) << 16);
            o.w = f2bf(acc[6] * inv) | (f2bf(acc[7] * inv) << 16);
            ((uint4*)outv)[(size_t)m * LPR + t] = o;
        } else {
            float* op = (float*)outv + (size_t)m * K + t * 8;
            float4 o0 = *(float4*)op, o1 = *(float4*)(op + 4);
            o0.x += acc[0] * inv; o0.y += acc[1] * inv;
            o0.z += acc[2] * inv; o0.w += acc[3] * inv;
            o1.x += acc[4] * inv; o1.y += acc[5] * inv;
            o1.z += acc[6] * inv; o1.w += acc[7] * inv;
            *(float4*)op = o0; *(float4*)(op + 4) = o1;
        }
    }
}

// ---- fused layer-1 + layer-2 GEMM ----
// Phase 1: h1[64][256] = relu([f2bf(x) | nb] @ Wt1^T + b1)  -> LDS (bf16,
//          16B-chunk XOR-swizzled so phase-2 reads are conflict-free).
// Phase 2: C2[64][128] = h1 @ Wt2^T ; cols 0..63 -> zb (bf16),
//          cols 64..127 (+b2) -> out fp32 for rows < cN2.
// Kills the 51.2 MB h1b write + 51.2 MB read and one kernel launch.
// LDS: 5k (As) + 20k (Bs) + 32k (H) = 58 KB -> 2 blocks/CU, 16 waves/CU.
__global__ __launch_bounds__(512) void gemm12(
        const float* __restrict__ X,            // [cN1][128] fp32
        const unsigned short* __restrict__ NB,  // [cN1][128] bf16
        const unsigned short* __restrict__ Wt1, // [256][256] bf16
        const float* __restrict__ b1,
        const unsigned short* __restrict__ Wt2, // [128][256] bf16
        const float* __restrict__ b2,
        unsigned short* __restrict__ zb,        // [cN1][64] bf16
        float* __restrict__ out) {              // [cN2][64] fp32
    __shared__ unsigned short As[64][40];
    __shared__ unsigned short Bs[256][40];
    __shared__ unsigned short H[64][256];       // swizzled: chunk ^= (row&7)

    const int tid = threadIdx.x;
    const int m0 = blockIdx.x * 64;
    const int lane = tid & 63, wave = tid >> 6;   // 8 waves
    const int quad = lane >> 4, l16 = lane & 15;

    // ---------------- phase 1 ----------------
    const int wcol = wave;                        // 32 output cols per wave
    f32x4 acc[4][2];
    #pragma unroll
    for (int i = 0; i < 4; ++i)
        #pragma unroll
        for (int j = 0; j < 2; ++j)
            acc[i][j] = (f32x4){0.f, 0.f, 0.f, 0.f};

    const int arow = tid >> 3, afq = tid & 7;     // 64 rows x 8 chunks (4 feats)
    const int gma  = m0 + arow;

    for (int kb = 0; kb < cH; kb += 32) {
        if (kb < cIN) {                           // A from fp32 x, convert in staging
            float4 a = {0.f, 0.f, 0.f, 0.f};
            if (gma < cN1)
                a = *(const float4*)(X + (size_t)gma * cIN + kb + afq * 4);
            uint2 v;
            v.x = f2bf(a.x) | (f2bf(a.y) << 16);
            v.y = f2bf(a.z) | (f2bf(a.w) << 16);
            *(uint2*)&As[arow][afq * 4] = v;
        } else {                                  // A from nb (already bf16)
            uint2 v = make_uint2(0u, 0u);
            if (gma < cN1)
                v = *(const uint2*)(NB + (size_t)gma * cIN + (kb - cIN) + afq * 4);
            *(uint2*)&As[arow][afq * 4] = v;
        }
        #pragma unroll
        for (int f = 0; f < 2; ++f) {             // B tile 256x32
            int idx = tid + f * 512;
            int row = idx >> 2, q = idx & 3;
            uint4 v = *(const uint4*)(Wt1 + (size_t)row * cH + kb + q * 8);
            *(uint4*)&Bs[row][q * 8] = v;
        }
        __syncthreads();

        bf16x8 a[4], bf[2];
        #pragma unroll
        for (int i = 0; i < 4; ++i)
            a[i] = *(const bf16x8*)&As[i * 16 + l16][quad * 8];
        #pragma unroll
        for (int j = 0; j < 2; ++j)
            bf[j] = *(const bf16x8*)&Bs[wcol * 32 + j * 16 + l16][quad * 8];
        #pragma unroll
        for (int i = 0; i < 4; ++i)
            #pragma unroll
            for (int j = 0; j < 2; ++j)
                acc[i][j] = __builtin_amdgcn_mfma_f32_16x16x32_bf16(
                    a[i], bf[j], acc[i][j], 0, 0, 0);
        __syncthreads();
    }

    // epilogue 1: bias + relu -> H (swizzled bf16); no global write
    float bv[2];
    #pragma unroll
    for (int j = 0; j < 2; ++j)
        bv[j] = b1[wcol * 32 + j * 16 + l16];
    #pragma unroll
    for (int i = 0; i < 4; ++i)
        #pragma unroll
        for (int r = 0; r < 4; ++r) {
            int row = i * 16 + quad * 4 + r;
            #pragma unroll
            for (int j = 0; j < 2; ++j) {
                int col = wcol * 32 + j * 16 + l16;
                float v = fmaxf(acc[i][j][r] + bv[j], 0.f);
                H[row][((((col >> 3) ^ (row & 7)) << 3) | (col & 7))] =
                    (unsigned short)f2bf(v);
            }
        }
    __syncthreads();

    // ---------------- phase 2 ----------------
    const int wr2 = wave >> 2, wc2 = wave & 3;    // 2x4 wave grid, 32x32 tiles
    f32x4 acc2[2][2];
    #pragma unroll
    for (int i = 0; i < 2; ++i)
        #pragma unroll
        for (int j = 0; j < 2; ++j)
            acc2[i][j] = (f32x4){0.f, 0.f, 0.f, 0.f};

    #pragma unroll
    for (int kb = 0; kb < cH; kb += 32) {
        bf16x8 a2[2], b2f[2];
        #pragma unroll
        for (int i = 0; i < 2; ++i) {
            int row = wr2 * 32 + i * 16 + l16;
            int kc = ((kb >> 3) + quad) ^ (row & 7);
            a2[i] = *(const bf16x8*)&H[row][kc << 3];
        }
        #pragma unroll
        for (int j = 0; j < 2; ++j) {
            int n = wc2 * 32 + j * 16 + l16;
            b2f[j] = *(const bf16x8*)(Wt2 + (size_t)n * cH + kb + quad * 8);
        }
        #pragma unroll
        for (int i = 0; i < 2; ++i)
            #pragma unroll
            for (int j = 0; j < 2; ++j)
                acc2[i][j] = __builtin_amdgcn_mfma_f32_16x16x32_bf16(
                    a2[i], b2f[j], acc2[i][j], 0, 0, 0);
    }

    // epilogue 2: n<64 -> zb (bf16, rows<cN1); n>=64 -> out (+b2, rows<cN2)
    #pragma unroll
    for (int i = 0; i < 2; ++i)
        #pragma unroll
        for (int r = 0; r < 4; ++r) {
            int gm = m0 + wr2 * 32 + i * 16 + quad * 4 + r;
            #pragma unroll
            for (int j = 0; j < 2; ++j) {
                int n = wc2 * 32 + j * 16 + l16;
                float v = acc2[i][j][r];
                if (n < cCLS) {
                    if (gm < cN1)
                        zb[(size_t)gm * cCLS + n] = (unsigned short)f2bf(v);
                } else if (gm < cN2) {
                    out[(size_t)gm * cCLS + (n - cCLS)] = v + b2[n - cCLS];
                }
            }
        }
}

extern "C" void kernel_launch(void* const* d_in, const int* in_sizes, int n_in,
                              void* d_out, int out_size, void* d_ws, size_t ws_size,
                              hipStream_t stream) {
    const float* x      = (const float*)d_in[0];
    const int*   src0   = (const int*)d_in[1];
    const int*   dst0   = (const int*)d_in[2];
    const int*   src1   = (const int*)d_in[3];
    const int*   dst1   = (const int*)d_in[4];
    const float* Wself1  = (const float*)d_in[7];
    const float* Wneigh1 = (const float*)d_in[8];
    const float* b1      = (const float*)d_in[9];
    const float* Wself2  = (const float*)d_in[10];
    const float* Wneigh2 = (const float*)d_in[11];
    const float* b2      = (const float*)d_in[12];
    float* out = (float*)d_out;

    // ---- workspace layout (zb aliases xq: xq dead after agg_i8) ----
    char* ws = (char*)d_ws;
    int* row0 = (int*)ws;                          // cN1+1
    int* row1 = row0 + (cN1 + 1);                  // cN2+1
    size_t off = (size_t)((cN1 + 1) + (cN2 + 1)) * sizeof(int);
    off = (off + 1023) & ~(size_t)1023;
    unsigned int*   xq = (unsigned int*)(ws + off);                                   // 25.6 MB
    unsigned short* zb = (unsigned short*)(ws + off); off += (size_t)cN0 * cIN;       // alias (12.8 MB used)
    unsigned short* nb  = (unsigned short*)(ws + off); off += (size_t)cN1 * cIN * 2; // 25.6 MB
    unsigned short* Wt1 = (unsigned short*)(ws + off); off += (size_t)cH * cH * 2;
    unsigned short* Wt2 = (unsigned short*)(ws + off); off += (size_t)2 * cCLS * cH * 2;

    // 1. all preprocessing in one dispatch (scatter row-ptr fill first)
    prep<<<R0B + R1B + WBLK + QBLK, 256, 0, stream>>>(
        x, Wself1, Wneigh1, Wneigh2, Wself2, dst0, dst1,
        xq, Wt1, Wt2, row0, row1);

    // 2. layer-1 aggregation (biased-u8 gather, packed-u16 accumulate)
    agg_i8<<<(cN1 + 3) / 4, 256, 0, stream>>>(
        (const uint2*)xq, src0, row0, nb, cN1);

    // 3. fused layer-1 GEMM + layer-2 GEMM (h1 never leaves LDS)
    gemm12<<<(cN1 + 63) / 64, 512, 0, stream>>>(
        x, nb, Wt1, b1, Wt2, b2, zb, out);

    // 4. layer-2 aggregation: out += segmean(zb)
    agg_wave<cCLS, true><<<(cN2 + 3) / 4, 256, 0, stream>>>(
        zb, src1, row1, out, cN2);
}